// Round 5
// baseline (78.989 us; speedup 1.0000x reference)
//
#include <hip/hip_runtime.h>

// Fused static-genome evaluation.
// Input dict order: loss(1), prev_loss(1), weights(24), p0..p7 (2048*4096 f32 each).
// Outputs: nodes 18,19,20,21 concatenated -> 4 * 8388608 f32.
//
// out0 = w16*w0*p0 + w16*w1*p1 + w17*w2*p2 + w17*w3*p3
// out1 = w18*w4*p4 + w18*w5*p5 + w19*w6*p6 + w19*w7*p7
// out2 = w20*w8*p0 + w21*w10*p1 + w21*w11*p6 + w20*w9*p7
// out3 = w22*w12*p2 + w23*w14*p3 + w23*w15*p4 + w22*w13*p5
//
// R5: A/B vs R3 — identical flat 1-float4/thread mapping, but PLAIN stores
// instead of nontemporal. NT didn't reduce FETCH (writes allocate in
// memory-side Infinity Cache regardless); its only measured effect may be
// the slow store-ack path (vmcnt drain to HBM holds waves alive before
// s_endpgm). Plain stores ack at XCD L2 and drain asynchronously.

typedef float fx4 __attribute__((ext_vector_type(4)));

__global__ __launch_bounds__(256) void genome_fused_kernel(
    const float* __restrict__ w,
    const float* __restrict__ p0, const float* __restrict__ p1,
    const float* __restrict__ p2, const float* __restrict__ p3,
    const float* __restrict__ p4, const float* __restrict__ p5,
    const float* __restrict__ p6, const float* __restrict__ p7,
    float* __restrict__ out, int n4, int n)
{
    const int i = blockIdx.x * 256 + threadIdx.x;
    if (i >= n4) return;

    const fx4* __restrict__ v0 = (const fx4*)p0;
    const fx4* __restrict__ v1 = (const fx4*)p1;
    const fx4* __restrict__ v2 = (const fx4*)p2;
    const fx4* __restrict__ v3 = (const fx4*)p3;
    const fx4* __restrict__ v4 = (const fx4*)p4;
    const fx4* __restrict__ v5 = (const fx4*)p5;
    const fx4* __restrict__ v6 = (const fx4*)p6;
    const fx4* __restrict__ v7 = (const fx4*)p7;

    // Issue all 8 independent loads before any use.
    fx4 a0 = v0[i];
    fx4 a1 = v1[i];
    fx4 a2 = v2[i];
    fx4 a3 = v3[i];
    fx4 a4 = v4[i];
    fx4 a5 = v5[i];
    fx4 a6 = v6[i];
    fx4 a7 = v7[i];

    // Coefficients (wave-uniform scalar loads; overlap with vector loads)
    const float c00 = w[16] * w[0];
    const float c01 = w[16] * w[1];
    const float c02 = w[17] * w[2];
    const float c03 = w[17] * w[3];

    const float c14 = w[18] * w[4];
    const float c15 = w[18] * w[5];
    const float c16 = w[19] * w[6];
    const float c17 = w[19] * w[7];

    const float c20 = w[20] * w[8];
    const float c27 = w[20] * w[9];
    const float c21 = w[21] * w[10];
    const float c26 = w[21] * w[11];

    const float c32 = w[22] * w[12];
    const float c35 = w[22] * w[13];
    const float c33 = w[23] * w[14];
    const float c34 = w[23] * w[15];

    fx4 r0 = c00*a0 + c01*a1 + c02*a2 + c03*a3;
    fx4 r1 = c14*a4 + c15*a5 + c16*a6 + c17*a7;
    fx4 r2 = c20*a0 + c21*a1 + c26*a6 + c27*a7;
    fx4 r3 = c32*a2 + c33*a3 + c34*a4 + c35*a5;

    fx4* __restrict__ o0 = (fx4*)out;
    fx4* __restrict__ o1 = (fx4*)(out + (size_t)n);
    fx4* __restrict__ o2 = (fx4*)(out + 2 * (size_t)n);
    fx4* __restrict__ o3 = (fx4*)(out + 3 * (size_t)n);

    o0[i] = r0;
    o1[i] = r1;
    o2[i] = r2;
    o3[i] = r3;
}

extern "C" void kernel_launch(void* const* d_in, const int* in_sizes, int n_in,
                              void* d_out, int out_size, void* d_ws, size_t ws_size,
                              hipStream_t stream) {
    // d_in order: 0=loss, 1=prev_loss, 2=weights[24], 3..10 = p0..p7
    const float* w  = (const float*)d_in[2];
    const float* p0 = (const float*)d_in[3];
    const float* p1 = (const float*)d_in[4];
    const float* p2 = (const float*)d_in[5];
    const float* p3 = (const float*)d_in[6];
    const float* p4 = (const float*)d_in[7];
    const float* p5 = (const float*)d_in[8];
    const float* p6 = (const float*)d_in[9];
    const float* p7 = (const float*)d_in[10];

    const int n  = in_sizes[3];      // 2048*4096 = 8388608, divisible by 4
    const int n4 = n / 4;            // float4 chunks

    const int block = 256;
    const int grid = (n4 + block - 1) / block;   // 8192 blocks, 1 float4/thread

    genome_fused_kernel<<<grid, block, 0, stream>>>(
        w, p0, p1, p2, p3, p4, p5, p6, p7, (float*)d_out, n4, n);
}

// Round 6
// 64.521 us; speedup vs baseline: 1.2242x; 1.2242x over previous
//
#include <hip/hip_runtime.h>

// Fused static-genome evaluation — FINAL (R3 structure, reverted after A/B).
// Input dict order: loss(1), prev_loss(1), weights(24), p0..p7 (2048*4096 f32 each).
// Outputs: nodes 18,19,20,21 concatenated -> 4 * 8388608 f32.
//
// out0 = w16*w0*p0 + w16*w1*p1 + w17*w2*p2 + w17*w3*p3
// out1 = w18*w4*p4 + w18*w5*p5 + w19*w6*p6 + w19*w7*p7
// out2 = w20*w8*p0 + w21*w10*p1 + w21*w11*p6 + w20*w9*p7
// out3 = w22*w12*p2 + w23*w14*p3 + w23*w15*p4 + w22*w13*p5
//
// Roofline accounting (measured): 402.6 MB fabric traffic/call
// (268 MB reads + 134 MB writes) at 64.6 us = 6.24 TB/s ~= 6.29 TB/s
// copy ceiling. NT stores bypass L2 write-allocate (plain stores: 5.1 TB/s).
// 1 float4/thread maximizes TLP (2/thread regressed: occupancy 74->56%).

typedef float fx4 __attribute__((ext_vector_type(4)));

__global__ __launch_bounds__(256) void genome_fused_kernel(
    const float* __restrict__ w,
    const float* __restrict__ p0, const float* __restrict__ p1,
    const float* __restrict__ p2, const float* __restrict__ p3,
    const float* __restrict__ p4, const float* __restrict__ p5,
    const float* __restrict__ p6, const float* __restrict__ p7,
    float* __restrict__ out, int n4, int n)
{
    const int i = blockIdx.x * 256 + threadIdx.x;
    if (i >= n4) return;

    const fx4* __restrict__ v0 = (const fx4*)p0;
    const fx4* __restrict__ v1 = (const fx4*)p1;
    const fx4* __restrict__ v2 = (const fx4*)p2;
    const fx4* __restrict__ v3 = (const fx4*)p3;
    const fx4* __restrict__ v4 = (const fx4*)p4;
    const fx4* __restrict__ v5 = (const fx4*)p5;
    const fx4* __restrict__ v6 = (const fx4*)p6;
    const fx4* __restrict__ v7 = (const fx4*)p7;

    // Issue all 8 independent loads before any use.
    fx4 a0 = v0[i];
    fx4 a1 = v1[i];
    fx4 a2 = v2[i];
    fx4 a3 = v3[i];
    fx4 a4 = v4[i];
    fx4 a5 = v5[i];
    fx4 a6 = v6[i];
    fx4 a7 = v7[i];

    // Coefficients (wave-uniform scalar loads; overlap with vector loads)
    const float c00 = w[16] * w[0];
    const float c01 = w[16] * w[1];
    const float c02 = w[17] * w[2];
    const float c03 = w[17] * w[3];

    const float c14 = w[18] * w[4];
    const float c15 = w[18] * w[5];
    const float c16 = w[19] * w[6];
    const float c17 = w[19] * w[7];

    const float c20 = w[20] * w[8];
    const float c27 = w[20] * w[9];
    const float c21 = w[21] * w[10];
    const float c26 = w[21] * w[11];

    const float c32 = w[22] * w[12];
    const float c35 = w[22] * w[13];
    const float c33 = w[23] * w[14];
    const float c34 = w[23] * w[15];

    fx4 r0 = c00*a0 + c01*a1 + c02*a2 + c03*a3;
    fx4 r1 = c14*a4 + c15*a5 + c16*a6 + c17*a7;
    fx4 r2 = c20*a0 + c21*a1 + c26*a6 + c27*a7;
    fx4 r3 = c32*a2 + c33*a3 + c34*a4 + c35*a5;

    fx4* __restrict__ o0 = (fx4*)out;
    fx4* __restrict__ o1 = (fx4*)(out + (size_t)n);
    fx4* __restrict__ o2 = (fx4*)(out + 2 * (size_t)n);
    fx4* __restrict__ o3 = (fx4*)(out + 3 * (size_t)n);

    __builtin_nontemporal_store(r0, &o0[i]);
    __builtin_nontemporal_store(r1, &o1[i]);
    __builtin_nontemporal_store(r2, &o2[i]);
    __builtin_nontemporal_store(r3, &o3[i]);
}

extern "C" void kernel_launch(void* const* d_in, const int* in_sizes, int n_in,
                              void* d_out, int out_size, void* d_ws, size_t ws_size,
                              hipStream_t stream) {
    // d_in order: 0=loss, 1=prev_loss, 2=weights[24], 3..10 = p0..p7
    const float* w  = (const float*)d_in[2];
    const float* p0 = (const float*)d_in[3];
    const float* p1 = (const float*)d_in[4];
    const float* p2 = (const float*)d_in[5];
    const float* p3 = (const float*)d_in[6];
    const float* p4 = (const float*)d_in[7];
    const float* p5 = (const float*)d_in[8];
    const float* p6 = (const float*)d_in[9];
    const float* p7 = (const float*)d_in[10];

    const int n  = in_sizes[3];      // 2048*4096 = 8388608, divisible by 4
    const int n4 = n / 4;            // float4 chunks

    const int block = 256;
    const int grid = (n4 + block - 1) / block;   // 8192 blocks, 1 float4/thread

    genome_fused_kernel<<<grid, block, 0, stream>>>(
        w, p0, p1, p2, p3, p4, p5, p6, p7, (float*)d_out, n4, n);
}